// Round 2
// 108.953 us; speedup vs baseline: 1.0399x; 1.0399x over previous
//
#include <hip/hip_runtime.h>

// Median filter 1D, k=9, replicate padding. x: [B*C rows = 2048, L=8192] fp32.
// Direct-load version: no LDS, no barrier. Each thread produces 4 outputs from
// 3 overlapping aligned float4 loads (elements g-4 .. g+7). L1/L2 absorb the
// 3x intra-wave read overlap; HBM traffic stays at 1x read + 1x write.

#define TILE 1024
#define BLOCK 256
#define HALO 4   // (k-1)/2 with k=9

// Native clang vector type: __builtin_nontemporal_store requires scalar /
// pointer / native-vector types (HIP_vector_type float4 is rejected).
typedef float floatx4 __attribute__((ext_vector_type(4)));

__device__ __forceinline__ void sort3(float a, float b, float c,
                                      float& lo, float& md, float& hi) {
    lo = fminf(fminf(a, b), c);                  // -> v_min3_f32
    hi = fmaxf(fmaxf(a, b), c);                  // -> v_max3_f32
    md = __builtin_amdgcn_fmed3f(a, b, c);       // -> v_med3_f32
}

// Exact median of 9: sort each triple, then med3(max(lows), med(mids), min(highs)).
__device__ __forceinline__ float med9(const float* p) {
    float l0, m0, h0, l1, m1, h1, l2, m2, h2;
    sort3(p[0], p[1], p[2], l0, m0, h0);
    sort3(p[3], p[4], p[5], l1, m1, h1);
    sort3(p[6], p[7], p[8], l2, m2, h2);
    float lo = fmaxf(fmaxf(l0, l1), l2);
    float md = __builtin_amdgcn_fmed3f(m0, m1, m2);
    float hi = fminf(fminf(h0, h1), h2);
    return __builtin_amdgcn_fmed3f(lo, md, hi);
}

__global__ __launch_bounds__(BLOCK) void median9_kernel(
    const float* __restrict__ x, float* __restrict__ out, int L, int tilesPerRow) {
    const int tid = threadIdx.x;
    const int row = blockIdx.x / tilesPerRow;
    const int g = (blockIdx.x % tilesPerRow) * TILE + 4 * tid;  // first output idx
    const long long row_base = (long long)row * L;
    const float* xr = x + row_base;

    float w[12];  // elements g-4 .. g+7 (window for outputs g .. g+3)

    if (g >= HALO && g + 2 * HALO <= L) {
        // Fast path: three aligned overlapping float4 loads. g % 4 == 0, so
        // xr + g - 4 is 16B aligned.
        const floatx4* p = (const floatx4*)(xr + g - HALO);
        floatx4 a = p[0], b = p[1], c = p[2];
        w[0] = a.x; w[1] = a.y; w[2]  = a.z; w[3]  = a.w;
        w[4] = b.x; w[5] = b.y; w[6]  = b.z; w[7]  = b.w;
        w[8] = c.x; w[9] = c.y; w[10] = c.z; w[11] = c.w;
    } else {
        // Boundary path (2 threads per row): scalar loads with replicate clamp.
#pragma unroll
        for (int j = 0; j < 12; ++j) {
            int pos = g - HALO + j;
            pos = min(max(pos, 0), L - 1);
            w[j] = xr[pos];
        }
    }

    floatx4 r;
    r.x = med9(w + 0);
    r.y = med9(w + 1);
    r.z = med9(w + 2);
    r.w = med9(w + 3);

    // Output is write-once, never re-read: nontemporal store to spare L2 for
    // the streaming input.
    __builtin_nontemporal_store(r, (floatx4*)(out + row_base + g));
}

extern "C" void kernel_launch(void* const* d_in, const int* in_sizes, int n_in,
                              void* d_out, int out_size, void* d_ws, size_t ws_size,
                              hipStream_t stream) {
    const float* x = (const float*)d_in[0];
    float* out = (float*)d_out;
    const int L = 8192;                 // static per the reference setup
    const int rows = in_sizes[0] / L;   // 32*64 = 2048
    const int tilesPerRow = L / TILE;   // 8
    const int nblocks = rows * tilesPerRow;
    median9_kernel<<<nblocks, BLOCK, 0, stream>>>(x, out, L, tilesPerRow);
}